// Round 4
// baseline (1383.254 us; speedup 1.0000x reference)
//
#include <hip/hip_runtime.h>

#define TPB 512
#define P_BLK 32        // parents per block (16 groups x 2 parents)
#define CH_I 4          // i-rows per chunk
#define NCHUNK 8        // 32 / CH_I
#define CH_FLOATS (P_BLK * CH_I * 16)   // 2048 floats = 8KB per chunk

__device__ __forceinline__ void load_lds16(const float* gsrc, float* ldsdst) {
    // width-16 global->LDS DMA: per-lane global src, wave-uniform LDS base (+lane*16B by HW)
    __builtin_amdgcn_global_load_lds((const __attribute__((address_space(1))) void*)gsrc,
                                     (__attribute__((address_space(3))) void*)ldsdst,
                                     16, 0, 0);
}

__global__ __launch_bounds__(TPB, 4) void equi_unpool_v4(
    const float* __restrict__ x_mv,    // [Np,32,16]
    const float* __restrict__ x_s,     // [Np,64]
    const float* __restrict__ skip_mv, // [Nc,32,16]
    const float* __restrict__ skip_s,  // [Nc,64]
    const float* __restrict__ w_mv,    // [32,32,9]
    const float* __restrict__ w_s2mv,  // [32,64]
    const float* __restrict__ w_mv2s,  // [64,32]
    const float* __restrict__ w_s2s,   // [64,64]
    const float* __restrict__ b_s,     // [64]
    float* __restrict__ out_mv,        // [Nc,32,16]
    float* __restrict__ out_s,         // [Nc,64]
    int n_parent, int stride)
{
    // Weights packed [i][o][12]: 0-8 = w_mv[o][i][*], 9/10 = w_mv2s[o][i]/[o+32][i],
    // slot 11 of rows i=0,1 overlays b_s. Lane stride 48B -> conflict-free b128 (R3: 0 conflicts).
    __shared__ float lw[12288];              // 48 KB
    __shared__ float xs[2][CH_FLOATS];       // 16 KB double-buffered x chunks -> total 64.25 KB

    const int tid = threadIdx.x;
    const int p0 = blockIdx.x * P_BLK;
    const int avail = n_parent - p0;
    const bool full_tile = (avail >= P_BLK);

    // DMA lane mapping: wave wv stages 1KB/chunk = parents 4wv..4wv+3, 256B each
    const int wv = tid >> 6;
    const int ln = tid & 63;
    const int pp = (wv << 2) + (ln >> 4);          // parent-local this lane stages
    const int fo = (ln & 15) << 2;                 // float offset within parent-chunk
    const float* gsrc_base = x_mv + (size_t)(p0 + pp) * 512 + fo;
    float* ldst0 = &xs[0][wv << 8];
    float* ldst1 = &xs[1][wv << 8];

    if (full_tile) load_lds16(gsrc_base, ldst0);   // prologue: chunk 0 (overlaps w-staging)

    // ---- stage weights ----
    #pragma unroll
    for (int base = 0; base < 12288; base += TPB) {
        int dst = base + tid;                      // dst-linear => conflict-free ds_write
        int t = dst / 12;
        int s = dst - t * 12;
        int oo = t & 31, ii = t >> 5;
        float v = 0.f;
        if (s < 9)        v = w_mv[oo * 288 + ii * 9 + s];
        else if (s == 9)  v = w_mv2s[oo * 32 + ii];
        else if (s == 10) v = w_mv2s[(oo + 32) * 32 + ii];
        else if (ii < 2)  v = b_s[ii * 32 + oo];
        lw[dst] = v;
    }
    __syncthreads();   // weights ready (also drains chunk-0 DMA; outside main loop, OK)

    const int o = tid & 31;                        // output channel
    const int g = tid >> 5;                        // parent group
    const int pA = p0 + g * 2;
    const bool active = (pA < n_parent);
    const bool hasB = (pA + 1 < n_parent);
    const int pB = hasB ? pA + 1 : pA;

    float a0[16], a1[16];
    #pragma unroll
    for (int j = 0; j < 16; ++j) { a0[j] = 0.f; a1[j] = 0.f; }
    float sA0 = 0.f, sA1 = 0.f, sB0 = 0.f, sB1 = 0.f;

    if (full_tile) {
        const int xoA = (g * 2) * (CH_I * 16);     // local parent offsets within chunk
        const int xoB = (g * 2 + 1) * (CH_I * 16);
        for (int c = 0; c < NCHUNK; ++c) {
            if (c + 1 < NCHUNK) {
                load_lds16(gsrc_base + (c + 1) * (CH_I * 16), (c & 1) ? ldst0 : ldst1);
                asm volatile("s_waitcnt vmcnt(1)" ::: "memory");   // chunk c complete, c+1 in flight
            } else {
                asm volatile("s_waitcnt vmcnt(0)" ::: "memory");
            }
            __builtin_amdgcn_s_barrier();
            __builtin_amdgcn_sched_barrier(0);

            const float* xA = &xs[c & 1][xoA];
            const float* xB = &xs[c & 1][xoB];
            #pragma unroll
            for (int il = 0; il < CH_I; ++il) {
                const int i = c * CH_I + il;
                float4 A0 = *(const float4*)(xA + il * 16 + 0);
                float4 A1 = *(const float4*)(xA + il * 16 + 4);
                float4 A2 = *(const float4*)(xA + il * 16 + 8);
                float4 A3 = *(const float4*)(xA + il * 16 + 12);
                float4 B0 = *(const float4*)(xB + il * 16 + 0);
                float4 B1 = *(const float4*)(xB + il * 16 + 4);
                float4 B2 = *(const float4*)(xB + il * 16 + 8);
                float4 B3 = *(const float4*)(xB + il * 16 + 12);
                const float* wp = &lw[(i * 32 + o) * 12];
                float4 wa = *(const float4*)(wp + 0);   // w0..w3
                float4 wb = *(const float4*)(wp + 4);   // w4..w7
                float4 wc = *(const float4*)(wp + 8);   // w8, wm0, wm1, (b_s overlay)

                a0[0]  += A0.x * wa.x;
                a0[1]  += A0.y * wa.y + A0.x * wb.y;
                a0[2]  += A0.z * wa.y;
                a0[3]  += A0.w * wa.y;
                a0[4]  += A1.x * wa.y;
                a0[5]  += A1.y * wa.z + A0.z * wb.z;
                a0[6]  += A1.z * wa.z + A0.w * wb.z;
                a0[7]  += A1.w * wa.z + A1.x * wb.z;
                a0[8]  += A2.x * wa.z;
                a0[9]  += A2.y * wa.z;
                a0[10] += A2.z * wa.z;
                a0[11] += A2.w * wa.w + A2.x * wb.w;
                a0[12] += A3.x * wa.w + A2.y * wb.w;
                a0[13] += A3.y * wa.w + A2.z * wb.w;
                a0[14] += A3.z * wa.w;
                a0[15] += A3.w * wb.x + A3.z * wc.x;
                sA0 += A0.x * wc.y;
                sA1 += A0.x * wc.z;

                a1[0]  += B0.x * wa.x;
                a1[1]  += B0.y * wa.y + B0.x * wb.y;
                a1[2]  += B0.z * wa.y;
                a1[3]  += B0.w * wa.y;
                a1[4]  += B1.x * wa.y;
                a1[5]  += B1.y * wa.z + B0.z * wb.z;
                a1[6]  += B1.z * wa.z + B0.w * wb.z;
                a1[7]  += B1.w * wa.z + B1.x * wb.z;
                a1[8]  += B2.x * wa.z;
                a1[9]  += B2.y * wa.z;
                a1[10] += B2.z * wa.z;
                a1[11] += B2.w * wa.w + B2.x * wb.w;
                a1[12] += B3.x * wa.w + B2.y * wb.w;
                a1[13] += B3.y * wa.w + B2.z * wb.w;
                a1[14] += B3.z * wa.w;
                a1[15] += B3.w * wb.x + B3.z * wc.x;
                sB0 += B0.x * wc.y;
                sB1 += B0.x * wc.z;
            }
            __builtin_amdgcn_s_barrier();
            __builtin_amdgcn_sched_barrier(0);
        }
    } else if (active) {
        // tail blocks: direct-global path (rare; correctness over speed)
        const float4* xAg = (const float4*)(x_mv + (size_t)pA * 512);
        const float4* xBg = (const float4*)(x_mv + (size_t)pB * 512);
        for (int i = 0; i < 32; ++i) {
            float4 A0 = xAg[i * 4 + 0], A1 = xAg[i * 4 + 1], A2 = xAg[i * 4 + 2], A3 = xAg[i * 4 + 3];
            float4 B0 = xBg[i * 4 + 0], B1 = xBg[i * 4 + 1], B2 = xBg[i * 4 + 2], B3 = xBg[i * 4 + 3];
            const float* wp = &lw[(i * 32 + o) * 12];
            float4 wa = *(const float4*)(wp + 0);
            float4 wb = *(const float4*)(wp + 4);
            float4 wc = *(const float4*)(wp + 8);
            a0[0]  += A0.x * wa.x;
            a0[1]  += A0.y * wa.y + A0.x * wb.y;
            a0[2]  += A0.z * wa.y;
            a0[3]  += A0.w * wa.y;
            a0[4]  += A1.x * wa.y;
            a0[5]  += A1.y * wa.z + A0.z * wb.z;
            a0[6]  += A1.z * wa.z + A0.w * wb.z;
            a0[7]  += A1.w * wa.z + A1.x * wb.z;
            a0[8]  += A2.x * wa.z;
            a0[9]  += A2.y * wa.z;
            a0[10] += A2.z * wa.z;
            a0[11] += A2.w * wa.w + A2.x * wb.w;
            a0[12] += A3.x * wa.w + A2.y * wb.w;
            a0[13] += A3.y * wa.w + A2.z * wb.w;
            a0[14] += A3.z * wa.w;
            a0[15] += A3.w * wb.x + A3.z * wc.x;
            sA0 += A0.x * wc.y;
            sA1 += A0.x * wc.z;
            a1[0]  += B0.x * wa.x;
            a1[1]  += B0.y * wa.y + B0.x * wb.y;
            a1[2]  += B0.z * wa.y;
            a1[3]  += B0.w * wa.y;
            a1[4]  += B1.x * wa.y;
            a1[5]  += B1.y * wa.z + B0.z * wb.z;
            a1[6]  += B1.z * wa.z + B0.w * wb.z;
            a1[7]  += B1.w * wa.z + B1.x * wb.z;
            a1[8]  += B2.x * wa.z;
            a1[9]  += B2.y * wa.z;
            a1[10] += B2.z * wa.z;
            a1[11] += B2.w * wa.w + B2.x * wb.w;
            a1[12] += B3.x * wa.w + B2.y * wb.w;
            a1[13] += B3.y * wa.w + B2.z * wb.w;
            a1[14] += B3.z * wa.w;
            a1[15] += B3.w * wb.x + B3.z * wc.x;
            sB0 += B0.x * wc.y;
            sB1 += B0.x * wc.z;
        }
    }

    if (!active) return;

    // ---- scalar inputs: s2mv (into a*[0]) and s2s ----
    const float4* xsA = (const float4*)(x_s + (size_t)pA * 64);
    const float4* xsB = (const float4*)(x_s + (size_t)pB * 64);
    const float4* wmv = (const float4*)(w_s2mv + (size_t)o * 64);
    const float4* wsa = (const float4*)(w_s2s + (size_t)o * 64);
    const float4* wsb = (const float4*)(w_s2s + (size_t)(o + 32) * 64);
    #pragma unroll 4
    for (int sc = 0; sc < 16; ++sc) {
        float4 xa = xsA[sc], xb = xsB[sc];
        float4 m = wmv[sc], wa = wsa[sc], wb = wsb[sc];
        a0[0] += xa.x * m.x + xa.y * m.y + xa.z * m.z + xa.w * m.w;
        a1[0] += xb.x * m.x + xb.y * m.y + xb.z * m.z + xb.w * m.w;
        sA0 += xa.x * wa.x + xa.y * wa.y + xa.z * wa.z + xa.w * wa.w;
        sA1 += xa.x * wb.x + xa.y * wb.y + xa.z * wb.z + xa.w * wb.w;
        sB0 += xb.x * wa.x + xb.y * wa.y + xb.z * wa.z + xb.w * wa.w;
        sB1 += xb.x * wb.x + xb.y * wb.y + xb.z * wb.z + xb.w * wb.w;
    }
    float bs0 = lw[(0 * 32 + o) * 12 + 11];   // b_s overlay
    float bs1 = lw[(1 * 32 + o) * 12 + 11];
    sA0 += bs0; sA1 += bs1; sB0 += bs0; sB1 += bs1;

    // ---- epilogue: broadcast to children, add skip, store (coalesced) ----
    for (int r = 0; r < stride; ++r) {
        size_t c = (size_t)pA * stride + r;
        const float4* sk = (const float4*)(skip_mv + c * 512 + o * 16);
        float4* om = (float4*)(out_mv + c * 512 + o * 16);
        float4 k0 = sk[0], k1 = sk[1], k2 = sk[2], k3 = sk[3];
        om[0] = make_float4(k0.x + a0[0],  k0.y + a0[1],  k0.z + a0[2],  k0.w + a0[3]);
        om[1] = make_float4(k1.x + a0[4],  k1.y + a0[5],  k1.z + a0[6],  k1.w + a0[7]);
        om[2] = make_float4(k2.x + a0[8],  k2.y + a0[9],  k2.z + a0[10], k2.w + a0[11]);
        om[3] = make_float4(k3.x + a0[12], k3.y + a0[13], k3.z + a0[14], k3.w + a0[15]);
        out_s[c * 64 + o]      = skip_s[c * 64 + o] + sA0;
        out_s[c * 64 + o + 32] = skip_s[c * 64 + o + 32] + sA1;
    }
    if (hasB) {
        for (int r = 0; r < stride; ++r) {
            size_t c = (size_t)pB * stride + r;
            const float4* sk = (const float4*)(skip_mv + c * 512 + o * 16);
            float4* om = (float4*)(out_mv + c * 512 + o * 16);
            float4 k0 = sk[0], k1 = sk[1], k2 = sk[2], k3 = sk[3];
            om[0] = make_float4(k0.x + a1[0],  k0.y + a1[1],  k0.z + a1[2],  k0.w + a1[3]);
            om[1] = make_float4(k1.x + a1[4],  k1.y + a1[5],  k1.z + a1[6],  k1.w + a1[7]);
            om[2] = make_float4(k2.x + a1[8],  k2.y + a1[9],  k2.z + a1[10], k2.w + a1[11]);
            om[3] = make_float4(k3.x + a1[12], k3.y + a1[13], k3.z + a1[14], k3.w + a1[15]);
            out_s[c * 64 + o]      = skip_s[c * 64 + o] + sB0;
            out_s[c * 64 + o + 32] = skip_s[c * 64 + o + 32] + sB1;
        }
    }
}

extern "C" void kernel_launch(void* const* d_in, const int* in_sizes, int n_in,
                              void* d_out, int out_size, void* d_ws, size_t ws_size,
                              hipStream_t stream) {
    const float* x_mv    = (const float*)d_in[0];
    const float* x_s     = (const float*)d_in[1];
    const float* skip_mv = (const float*)d_in[2];
    const float* skip_s  = (const float*)d_in[3];
    const float* w_mv    = (const float*)d_in[4];
    const float* w_s2mv  = (const float*)d_in[5];
    const float* w_mv2s  = (const float*)d_in[6];
    const float* w_s2s   = (const float*)d_in[7];
    const float* b_s     = (const float*)d_in[8];

    const int n_parent = in_sizes[0] / 512;   // [Np,32,16]
    const int n_child  = in_sizes[2] / 512;   // [Nc,32,16]
    const int stride   = n_child / n_parent;

    float* out_mv = (float*)d_out;
    float* out_s  = out_mv + (size_t)n_child * 512;

    const int blocks = (n_parent + P_BLK - 1) / P_BLK;
    equi_unpool_v4<<<blocks, TPB, 0, stream>>>(
        x_mv, x_s, skip_mv, skip_s, w_mv, w_s2mv, w_mv2s, w_s2s, b_s,
        out_mv, out_s, n_parent, stride);
}